// Round 11
// baseline (145.794 us; speedup 1.0000x reference)
//
#include <hip/hip_runtime.h>
#include <hip/hip_bf16.h>
#include <cstdint>

using bf16x8 = __attribute__((ext_vector_type(8))) __bf16;
using f32x4  = __attribute__((ext_vector_type(4))) float;

#define LOG2E 1.4426950408889634f

__device__ inline void gload16(__bf16* lds, const __bf16* g) {
    __builtin_amdgcn_global_load_lds((const __attribute__((address_space(1))) void*)g,
                                     (__attribute__((address_space(3))) void*)lds, 16, 0, 0);
}
__device__ inline void wait_barrier4() {
    asm volatile("s_waitcnt vmcnt(4)" ::: "memory");
    __builtin_amdgcn_s_barrier();
}
__device__ inline void wait_barrier0() {
    asm volatile("s_waitcnt vmcnt(0)" ::: "memory");
    __builtin_amdgcn_s_barrier();
}

// ---------------------------------------------------------------------------
// RMSNorm: one block (256 threads) per row of 1024 fp32 -> bf16
// ---------------------------------------------------------------------------
__global__ __launch_bounds__(256) void rmsnorm_kernel(const float* __restrict__ x,
                                                      const float* __restrict__ w,
                                                      __bf16* __restrict__ xn) {
    const int row = blockIdx.x;
    const float4 v = reinterpret_cast<const float4*>(x + (size_t)row * 1024)[threadIdx.x];
    float ss = v.x * v.x + v.y * v.y + v.z * v.z + v.w * v.w;
#pragma unroll
    for (int i = 1; i < 64; i <<= 1) ss += __shfl_xor(ss, i);
    __shared__ float part[4];
    if ((threadIdx.x & 63) == 0) part[threadIdx.x >> 6] = ss;
    __syncthreads();
    const float total = part[0] + part[1] + part[2] + part[3];
    const float scale = rsqrtf(total * (1.0f / 1024.0f) + 1.1920929e-07f);
    const float4 wv = reinterpret_cast<const float4*>(w)[threadIdx.x];
    union { __bf16 h[4]; uint2 u; } pk;
    pk.h[0] = (__bf16)(v.x * scale * wv.x);
    pk.h[1] = (__bf16)(v.y * scale * wv.y);
    pk.h[2] = (__bf16)(v.z * scale * wv.z);
    pk.h[3] = (__bf16)(v.w * scale * wv.w);
    reinterpret_cast<uint2*>(xn + (size_t)row * 1024)[threadIdx.x] = pk.u;
}

// ---------------------------------------------------------------------------
// Transpose + cast: in (K x N) fp32 row-major -> out (N x K) bf16 row-major
// ---------------------------------------------------------------------------
__global__ void transpose_cast_kernel(const float* __restrict__ in,
                                      __bf16* __restrict__ out, int K, int N) {
    __shared__ float tile[32][33];
    const int n0 = blockIdx.x * 32, k0 = blockIdx.y * 32;
#pragma unroll
    for (int r = threadIdx.y; r < 32; r += 8)
        tile[r][threadIdx.x] = in[(size_t)(k0 + r) * N + n0 + threadIdx.x];
    __syncthreads();
#pragma unroll
    for (int r = threadIdx.y; r < 32; r += 8)
        out[(size_t)(n0 + r) * K + k0 + threadIdx.x] = (__bf16)tile[threadIdx.x][r];
}

// ---------------------------------------------------------------------------
// cos/sin table: csin[pos*64+d] = (cos, sin) of rot[pos][d]. 262144 entries.
// ---------------------------------------------------------------------------
__global__ __launch_bounds__(256) void csin_kernel(const float* __restrict__ rot,
                                                   float2* __restrict__ csin) {
    const int i = blockIdx.x * 256 + threadIdx.x;
    float s, c;
    sincosf(rot[i], &s, &c);
    csin[i] = make_float2(c, s);
}

// ---------------------------------------------------------------------------
// RoPE (table-based) in-place on qk [8192][1024]; q (cols<512) also scaled by
// d^-0.5 * log2(e). One wave per (b,pos): lane = h*8 + d-quad.
// ---------------------------------------------------------------------------
__global__ __launch_bounds__(256) void rope_kernel(__bf16* __restrict__ qk,
                                                   const float2* __restrict__ csin) {
    const int row = blockIdx.x * 4 + (threadIdx.x >> 6);   // b*4096+pos
    const int lane = threadIdx.x & 63;
    const int h = lane >> 3, dl = (lane & 7) * 4;
    const int pos = row & 4095;
    const float4 csA = *reinterpret_cast<const float4*>(&csin[pos * 64 + dl]);
    const float4 csB = *reinterpret_cast<const float4*>(&csin[pos * 64 + dl + 2]);
    const float4 csC = *reinterpret_cast<const float4*>(&csin[pos * 64 + dl + 32]);
    const float4 csD = *reinterpret_cast<const float4*>(&csin[pos * 64 + dl + 34]);
    const float c0[4] = {csA.x, csA.z, csB.x, csB.z};
    const float s0[4] = {csA.y, csA.w, csB.y, csB.w};
    const float c1[4] = {csC.x, csC.z, csD.x, csD.z};
    const float s1[4] = {csC.y, csC.w, csD.y, csD.w};
    __bf16* p = qk + (size_t)row * 1024 + h * 64 + dl;
    const float qs = 0.125f * LOG2E;
#pragma unroll
    for (int part = 0; part < 2; ++part) {      // q then k
        __bf16* pp = p + part * 512;
        const float sc = part ? 1.0f : qs;
        union { uint2 u; __bf16 hh[4]; } va, vb, oa, ob;
        va.u = *reinterpret_cast<const uint2*>(pp);
        vb.u = *reinterpret_cast<const uint2*>(pp + 32);
#pragma unroll
        for (int j = 0; j < 4; ++j) {
            const float a = (float)va.hh[j], b2 = (float)vb.hh[j];
            oa.hh[j] = (__bf16)((a * c0[j] - b2 * s0[j]) * sc);
            ob.hh[j] = (__bf16)((b2 * c1[j] + a * s1[j]) * sc);
        }
        *reinterpret_cast<uint2*>(pp)      = oa.u;
        *reinterpret_cast<uint2*>(pp + 32) = ob.u;
    }
}

// ---------------------------------------------------------------------------
// GEMM: C(MxN) = A(MxK) @ Bt(NxK)^T, bf16 in, fp32 accum.
// Ring-3 LDS, counted vmcnt(4) barriers (T3/T4). Epilogue: per-wave LDS
// transpose (reusing As after the final drain barrier) -> 16B-packed
// coalesced stores (was 64 scalar stores/thread: ~20us of store issue).
// MODE 0: float output, ld = N. MODE 1 (QKV): cols <1024 -> qk buf
// [8192][1024] bf16; v -> vt[1024][4096] transposed + kappa-permuted.
// ---------------------------------------------------------------------------
template <typename OutT, int MODE>
__global__ __launch_bounds__(256) void gemm_bt(const __bf16* __restrict__ A,
                                               const __bf16* __restrict__ Bt,
                                               OutT* __restrict__ C,
                                               __bf16* __restrict__ vt,
                                               int M, int N, int K) {
    __shared__ __align__(16) __bf16 As[3][128 * 32];
    __shared__ __align__(16) __bf16 Bs[3][128 * 32];
    const int bm = blockIdx.y, bn = blockIdx.x;
    const int tid = threadIdx.x;
    const int w = tid >> 6, l = tid & 63, lg = l >> 4, lr = l & 15;
    const int wr = w >> 1, wc = w & 1;
    const __bf16* Ab = A + (size_t)(bm * 128) * K;
    const __bf16* Bb = Bt + (size_t)(bn * 128) * K;
    const int srow = tid >> 2, scol = (tid & 3) * 8;
    const __bf16* Asrc = Ab + (size_t)srow * K + scol;
    const __bf16* Bsrc = Bb + (size_t)srow * K + scol;

    auto stage = [&](int k2) {
        const int nx = k2 % 3;
        const int off = k2 * 32;
        gload16(&As[nx][tid * 8],        Asrc + off);
        gload16(&As[nx][2048 + tid * 8], Asrc + (size_t)64 * K + off);
        gload16(&Bs[nx][tid * 8],        Bsrc + off);
        gload16(&Bs[nx][2048 + tid * 8], Bsrc + (size_t)64 * K + off);
    };

    const int NS = K >> 5;
    f32x4 acc[4][4] = {};
    stage(0);
    stage(1);
    wait_barrier4();
    for (int k = 0; k < NS; ++k) {
        const bool more = (k + 2 < NS);
        if (more) stage(k + 2);
        const __bf16* Ac = &As[k % 3][0];
        const __bf16* Bc = &Bs[k % 3][0];
        bf16x8 af[4], bfr[4];
#pragma unroll
        for (int m = 0; m < 4; ++m)
            af[m] = *reinterpret_cast<const bf16x8*>(Ac + (wr * 64 + m * 16 + lr) * 32 + lg * 8);
#pragma unroll
        for (int nn = 0; nn < 4; ++nn)
            bfr[nn] = *reinterpret_cast<const bf16x8*>(Bc + (wc * 64 + nn * 16 + lr) * 32 + lg * 8);
#pragma unroll
        for (int m = 0; m < 4; ++m)
#pragma unroll
            for (int nn = 0; nn < 4; ++nn)
                acc[m][nn] = __builtin_amdgcn_mfma_f32_16x16x32_bf16(af[m], bfr[nn],
                                                                     acc[m][nn], 0, 0, 0);
        if (more) wait_barrier4();
        else      wait_barrier0();        // final drain: LDS reusable after
    }

    // -------- epilogue --------
    const int cb = bn * 128 + wc * 64;
    if constexpr (MODE == 1) {
        if (cb >= 1024) {                 // v -> vt transposed + kappa (no LDS)
#pragma unroll
            for (int m = 0; m < 4; ++m) {
                const int rg = bm * 128 + wr * 64 + m * 16 + 4 * lg;
                const int bidx = rg >> 12, pos0 = rg & 4095;
                const int a0 = pos0 & 63;
                const int cp = 32 * (a0 >> 5) + 8 * ((a0 >> 2) & 3) + 4 * ((a0 >> 4) & 1);
                const int nbase = (pos0 & ~63) + cp;
#pragma unroll
                for (int nn = 0; nn < 4; ++nn) {
                    const int col = cb + nn * 16 + lr - 1024;
                    const int hh = col >> 6, dd = col & 63;
                    union { __bf16 h4[4]; uint2 u; } pk2;
#pragma unroll
                    for (int r = 0; r < 4; ++r) pk2.h4[r] = (__bf16)acc[m][nn][r];
                    *reinterpret_cast<uint2*>(&vt[((size_t)(bidx * 8 + hh) * 64 + dd) * 4096 + nbase]) = pk2.u;
                }
            }
            return;
        }
    }
    // LDS-transposed coalesced stores (per-wave buffer; no cross-wave sync)
    float* tb = reinterpret_cast<float*>(&As[0][0]) + w * 1088;   // [16][68]
    const int row = l >> 2, c4 = (l & 3) * 16;
#pragma unroll
    for (int m = 0; m < 4; ++m) {
#pragma unroll
        for (int nn = 0; nn < 4; ++nn)
#pragma unroll
            for (int r = 0; r < 4; ++r)
                tb[(4 * lg + r) * 68 + nn * 16 + lr] = acc[m][nn][r];
        const int rg2 = bm * 128 + wr * 64 + m * 16 + row;
        float v[16];
#pragma unroll
        for (int j = 0; j < 4; ++j)
            *reinterpret_cast<float4*>(v + 4 * j) =
                *reinterpret_cast<const float4*>(tb + row * 68 + c4 + 4 * j);
        if constexpr (MODE == 1) {        // bf16 qk output, ld=1024
            union { __bf16 h16[16]; uint4 u4[2]; } ob;
#pragma unroll
            for (int j = 0; j < 16; ++j) ob.h16[j] = (__bf16)v[j];
            uint4* dst = reinterpret_cast<uint4*>(C + (size_t)rg2 * 1024 + cb + c4);
            dst[0] = ob.u4[0];
            dst[1] = ob.u4[1];
        } else {                          // float output, ld=N
#pragma unroll
            for (int j = 0; j < 4; ++j)
                *reinterpret_cast<float4*>(&C[(size_t)rg2 * N + cb + c4 + 4 * j]) =
                    *reinterpret_cast<const float4*>(v + 4 * j);
        }
    }
}

// ---------------------------------------------------------------------------
// Causal flash attention v11: ring-3 LDS (48KB -> 3 blocks/CU = 12 waves),
// 1024 single-segment blocks: xcd = bid&7, bh = 2*xcd + (j&1),
// qt = 63 - (j>>1) (heavy-first per XCD; 2 heads/XCD L2-resident KV).
// Zero-VALU staging (global_load_lds, pre-swizzled source), P in registers
// (kappa-permuted vt), deferred reductions, defer-max, unroll x6 static.
// ---------------------------------------------------------------------------
__global__ __launch_bounds__(256) void attn_kernel(const __bf16* __restrict__ qkp,
                                                   const __bf16* __restrict__ vt,
                                                   __bf16* __restrict__ attn_out) {
    const int bid = blockIdx.x;                      // 1024 blocks
    const int j = bid >> 3;                          // 0..127 per XCD
    const int bh = 2 * (bid & 7) + (j & 1);
    const int qt = 63 - (j >> 1);                    // heavy blocks first
    const int b = bh >> 3, h = bh & 7;
    const int tid = threadIdx.x;
    const int w = tid >> 6, l = tid & 63, lg = l >> 4, lr = l & 15;

    __shared__ __align__(16) __bf16 Ks[3][64 * 64];
    __shared__ __align__(16) __bf16 Vs[3][64 * 64];

    const __bf16* qbase = qkp + (size_t)b * 4096 * 1024 + h * 64;
    const __bf16* kbase = qbase + 512;
    const __bf16* vtb   = vt + (size_t)(b * 8 + h) * 64 * 4096;

    const int sr = tid >> 3;
    const int sc = ((tid & 7) ^ (sr & 7)) * 8;
    const __bf16* kp = kbase + (size_t)sr * 1024 + sc;
    const __bf16* vp = vtb + (size_t)sr * 4096 + sc;

    const int xel = (lr & 7) * 8;                    // read-side swizzle

    const int wq0 = qt * 64 + 16 * w;
    const int nkt = qt + 1;

    bf16x8 Qf[2];
#pragma unroll
    for (int kh = 0; kh < 2; ++kh)
        Qf[kh] = *reinterpret_cast<const bf16x8*>(
            qbase + (size_t)(wq0 + lr) * 1024 + 32 * kh + 8 * lg);

    f32x4 O[4] = {};
    float m_ = -1e30f, l_ = 0.0f;

    auto stage2 = [&](__bf16* kdst, __bf16* vdst) {
        gload16(kdst + tid * 8,         kp);
        gload16(kdst + (tid + 256) * 8, kp + 32 * 1024);
        gload16(vdst + tid * 8,         vp);
        gload16(vdst + (tid + 256) * 8, vp + 32 * 4096);
        kp += 64 * 1024;
        vp += 64;
    };
    auto qk_step = [&](f32x4 (&S)[4], const __bf16* kb) {
        __builtin_amdgcn_s_setprio(1);
#pragma unroll
        for (int jt = 0; jt < 4; ++jt) {
            const __bf16* kr = kb + (16 * jt + lr) * 64;
            const bf16x8 Kf0 = *reinterpret_cast<const bf16x8*>(kr + ((8 * lg) ^ xel));
            const bf16x8 Kf1 = *reinterpret_cast<const bf16x8*>(kr + ((32 + 8 * lg) ^ xel));
            f32x4 z = {};
            z = __builtin_amdgcn_mfma_f32_16x16x32_bf16(Kf0, Qf[0], z, 0, 0, 0);
            S[jt] = __builtin_amdgcn_mfma_f32_16x16x32_bf16(Kf1, Qf[1], z, 0, 0, 0);
        }
        __builtin_amdgcn_s_setprio(0);
    };
    auto smpv = [&](f32x4 (&SC)[4], const __bf16* vb, bool domask) {
        if (domask) {
#pragma unroll
            for (int jt = 0; jt < 4; ++jt)
#pragma unroll
                for (int r = 0; r < 4; ++r)
                    if (16 * jt + 4 * lg + r > 16 * w + lr) SC[jt][r] = -1e30f;
        }
        float mx = -1e30f;
#pragma unroll
        for (int jt = 0; jt < 4; ++jt)
            mx = fmaxf(mx, fmaxf(fmaxf(SC[jt][0], SC[jt][1]), fmaxf(SC[jt][2], SC[jt][3])));
        if (__any(mx > m_ + 8.0f)) {
            mx = fmaxf(mx, __shfl_xor(mx, 16));
            mx = fmaxf(mx, __shfl_xor(mx, 32));
            const float mn = fmaxf(m_, mx);
            const float alpha = __builtin_amdgcn_exp2f(m_ - mn);
            m_ = mn;
            l_ *= alpha;
#pragma unroll
            for (int dt = 0; dt < 4; ++dt) O[dt] *= alpha;
        }
        float sum = 0.0f;
#pragma unroll
        for (int jt = 0; jt < 4; ++jt)
#pragma unroll
            for (int r = 0; r < 4; ++r) {
                const float pv = __builtin_amdgcn_exp2f(SC[jt][r] - m_);
                SC[jt][r] = pv;
                sum += pv;
            }
        l_ += sum;
        __builtin_amdgcn_s_setprio(1);
#pragma unroll
        for (int s = 0; s < 2; ++s) {
            bf16x8 Pf;
#pragma unroll
            for (int i = 0; i < 8; ++i)
                Pf[i] = (__bf16)SC[2 * s + (i >> 2)][i & 3];
#pragma unroll
            for (int dt = 0; dt < 4; ++dt) {
                const bf16x8 Vf = *reinterpret_cast<const bf16x8*>(
                    vb + (16 * dt + lr) * 64 + ((32 * s + 8 * lg) ^ xel));
                O[dt] = __builtin_amdgcn_mfma_f32_16x16x32_bf16(Vf, Pf, O[dt], 0, 0, 0);
            }
        }
        __builtin_amdgcn_s_setprio(0);
    };

    f32x4 S0[4], S1[4];
    int t = 0;

    // prologue: stage tiles 0,1; S0 = QK(0)
    stage2(Ks[0], Vs[0]);
    stage2(Ks[1], Vs[1]);
    __syncthreads();
    qk_step(S0, Ks[0]);

    // main loop: 6 statically-indexed bodies, all pre-diagonal
    for (; t + 8 <= nkt; t += 6) {
        stage2(Ks[2], Vs[2]); qk_step(S1, Ks[1]); smpv(S0, Vs[0], false); __syncthreads();
        stage2(Ks[0], Vs[0]); qk_step(S0, Ks[2]); smpv(S1, Vs[1], false); __syncthreads();
        stage2(Ks[1], Vs[1]); qk_step(S1, Ks[0]); smpv(S0, Vs[2], false); __syncthreads();
        stage2(Ks[2], Vs[2]); qk_step(S0, Ks[1]); smpv(S1, Vs[0], false); __syncthreads();
        stage2(Ks[0], Vs[0]); qk_step(S1, Ks[2]); smpv(S0, Vs[1], false); __syncthreads();
        stage2(Ks[1], Vs[1]); qk_step(S0, Ks[0]); smpv(S1, Vs[2], false); __syncthreads();
    }

    // tail: <=7 tiles, dynamic ring indices, mask on the last tile
    {
        f32x4 Sp[4];
#pragma unroll
        for (int jt = 0; jt < 4; ++jt) Sp[jt] = S0[jt];
        for (; t < nkt; ++t) {
            if (t + 2 < nkt) stage2(Ks[(t + 2) % 3], Vs[(t + 2) % 3]);
            f32x4 Sn[4];
            if (t + 1 < nkt) qk_step(Sn, Ks[(t + 1) % 3]);
            smpv(Sp, Vs[t % 3], t == nkt - 1);
            __syncthreads();
#pragma unroll
            for (int jt = 0; jt < 4; ++jt) Sp[jt] = Sn[jt];
        }
    }

    // epilogue: deferred row-sum of l, then O / l
    float lt = l_;
    lt += __shfl_xor(lt, 16);
    lt += __shfl_xor(lt, 32);
    const float inv = 1.0f / lt;
    __bf16* op = attn_out + ((size_t)b * 4096 + wq0 + lr) * 512 + h * 64;
#pragma unroll
    for (int dt = 0; dt < 4; ++dt) {
        union { __bf16 h4[4]; uint2 u; } ow;
#pragma unroll
        for (int r = 0; r < 4; ++r) ow.h4[r] = (__bf16)(O[dt][r] * inv);
        *reinterpret_cast<uint2*>(op + 16 * dt + 4 * lg) = ow.u;
    }
}

// ---------------------------------------------------------------------------
extern "C" void kernel_launch(void* const* d_in, const int* in_sizes, int n_in,
                              void* d_out, int out_size, void* d_ws, size_t ws_size,
                              hipStream_t stream) {
    (void)in_sizes; (void)n_in; (void)out_size; (void)ws_size;
    const float* x    = (const float*)d_in[0];
    const float* rot  = (const float*)d_in[1];
    const float* rmsw = (const float*)d_in[2];
    const float* wqkv = (const float*)d_in[3];
    const float* wout = (const float*)d_in[4];
    float* out = (float*)d_out;

    char* ws = (char*)d_ws;
    __bf16* xn    = (__bf16*)ws;                       // 16,777,216 B
    __bf16* wqkvt = (__bf16*)(ws + 16777216);          //  3,145,728 B
    __bf16* woutt = (__bf16*)(ws + 16777216 + 3145728);//  1,048,576 B
    __bf16* aout  = (__bf16*)(ws + 16777216 + 3145728 + 1048576); // 8,388,608 B
    // d_out during pipeline: qk [0,16.78M), csin [16.78M,18.87M),
    // vt [18.87M,27.26M) — all dead before the final GEMM overwrites d_out.
    __bf16* qk   = (__bf16*)d_out;
    float2* csin = (float2*)((char*)d_out + 16777216);
    __bf16* vt   = (__bf16*)((char*)d_out + 18874368);

    rmsnorm_kernel<<<8192, 256, 0, stream>>>(x, rmsw, xn);
    transpose_cast_kernel<<<dim3(48, 32), dim3(32, 8), 0, stream>>>(wqkv, wqkvt, 1024, 1536);
    transpose_cast_kernel<<<dim3(32, 16), dim3(32, 8), 0, stream>>>(wout, woutt, 512, 1024);
    csin_kernel<<<1024, 256, 0, stream>>>(rot, csin);
    gemm_bt<__bf16, 1><<<dim3(12, 64), 256, 0, stream>>>(xn, wqkvt, qk, vt, 8192, 1536, 1024);
    rope_kernel<<<2048, 256, 0, stream>>>(qk, csin);
    attn_kernel<<<1024, 256, 0, stream>>>(qk, vt, aout);
    gemm_bt<float, 0><<<dim3(8, 64), 256, 0, stream>>>(aout, woutt, out, nullptr, 8192, 1024, 512);
}

// Round 13
// 138.617 us; speedup vs baseline: 1.0518x; 1.0518x over previous
//
#include <hip/hip_runtime.h>
#include <hip/hip_bf16.h>
#include <cstdint>

using bf16x8 = __attribute__((ext_vector_type(8))) __bf16;
using f32x4  = __attribute__((ext_vector_type(4))) float;

#define LOG2E 1.4426950408889634f

__device__ inline void gload16(__bf16* lds, const __bf16* g) {
    __builtin_amdgcn_global_load_lds((const __attribute__((address_space(1))) void*)g,
                                     (__attribute__((address_space(3))) void*)lds, 16, 0, 0);
}
__device__ inline void wait_barrier4() {
    asm volatile("s_waitcnt vmcnt(4)" ::: "memory");
    __builtin_amdgcn_s_barrier();
}
__device__ inline void wait_barrier0() {
    asm volatile("s_waitcnt vmcnt(0)" ::: "memory");
    __builtin_amdgcn_s_barrier();
}

// ---------------------------------------------------------------------------
// RMSNorm: one block (256 threads) per row of 1024 fp32 -> bf16
// ---------------------------------------------------------------------------
__global__ __launch_bounds__(256) void rmsnorm_kernel(const float* __restrict__ x,
                                                      const float* __restrict__ w,
                                                      __bf16* __restrict__ xn) {
    const int row = blockIdx.x;
    const float4 v = reinterpret_cast<const float4*>(x + (size_t)row * 1024)[threadIdx.x];
    float ss = v.x * v.x + v.y * v.y + v.z * v.z + v.w * v.w;
#pragma unroll
    for (int i = 1; i < 64; i <<= 1) ss += __shfl_xor(ss, i);
    __shared__ float part[4];
    if ((threadIdx.x & 63) == 0) part[threadIdx.x >> 6] = ss;
    __syncthreads();
    const float total = part[0] + part[1] + part[2] + part[3];
    const float scale = rsqrtf(total * (1.0f / 1024.0f) + 1.1920929e-07f);
    const float4 wv = reinterpret_cast<const float4*>(w)[threadIdx.x];
    union { __bf16 h[4]; uint2 u; } pk;
    pk.h[0] = (__bf16)(v.x * scale * wv.x);
    pk.h[1] = (__bf16)(v.y * scale * wv.y);
    pk.h[2] = (__bf16)(v.z * scale * wv.z);
    pk.h[3] = (__bf16)(v.w * scale * wv.w);
    reinterpret_cast<uint2*>(xn + (size_t)row * 1024)[threadIdx.x] = pk.u;
}

// ---------------------------------------------------------------------------
// Transpose + cast: in (K x N) fp32 row-major -> out (N x K) bf16 row-major
// ---------------------------------------------------------------------------
__global__ void transpose_cast_kernel(const float* __restrict__ in,
                                      __bf16* __restrict__ out, int K, int N) {
    __shared__ float tile[32][33];
    const int n0 = blockIdx.x * 32, k0 = blockIdx.y * 32;
#pragma unroll
    for (int r = threadIdx.y; r < 32; r += 8)
        tile[r][threadIdx.x] = in[(size_t)(k0 + r) * N + n0 + threadIdx.x];
    __syncthreads();
#pragma unroll
    for (int r = threadIdx.y; r < 32; r += 8)
        out[(size_t)(n0 + r) * K + k0 + threadIdx.x] = (__bf16)tile[threadIdx.x][r];
}

// ---------------------------------------------------------------------------
// cos/sin table: csin[pos*64+d] = (cos, sin) of rot[pos][d]. 262144 entries.
// ---------------------------------------------------------------------------
__global__ __launch_bounds__(256) void csin_kernel(const float* __restrict__ rot,
                                                   float2* __restrict__ csin) {
    const int i = blockIdx.x * 256 + threadIdx.x;
    float s, c;
    sincosf(rot[i], &s, &c);
    csin[i] = make_float2(c, s);
}

// ---------------------------------------------------------------------------
// RoPE (table-based) in-place on qk [8192][1024]; q (cols<512) also scaled by
// d^-0.5 * log2(e). One wave per (b,pos): lane = h*8 + d-quad.
// ---------------------------------------------------------------------------
__global__ __launch_bounds__(256) void rope_kernel(__bf16* __restrict__ qk,
                                                   const float2* __restrict__ csin) {
    const int row = blockIdx.x * 4 + (threadIdx.x >> 6);   // b*4096+pos
    const int lane = threadIdx.x & 63;
    const int h = lane >> 3, dl = (lane & 7) * 4;
    const int pos = row & 4095;
    const float4 csA = *reinterpret_cast<const float4*>(&csin[pos * 64 + dl]);
    const float4 csB = *reinterpret_cast<const float4*>(&csin[pos * 64 + dl + 2]);
    const float4 csC = *reinterpret_cast<const float4*>(&csin[pos * 64 + dl + 32]);
    const float4 csD = *reinterpret_cast<const float4*>(&csin[pos * 64 + dl + 34]);
    const float c0[4] = {csA.x, csA.z, csB.x, csB.z};
    const float s0[4] = {csA.y, csA.w, csB.y, csB.w};
    const float c1[4] = {csC.x, csC.z, csD.x, csD.z};
    const float s1[4] = {csC.y, csC.w, csD.y, csD.w};
    __bf16* p = qk + (size_t)row * 1024 + h * 64 + dl;
    const float qs = 0.125f * LOG2E;
#pragma unroll
    for (int part = 0; part < 2; ++part) {      // q then k
        __bf16* pp = p + part * 512;
        const float sc = part ? 1.0f : qs;
        union { uint2 u; __bf16 hh[4]; } va, vb, oa, ob;
        va.u = *reinterpret_cast<const uint2*>(pp);
        vb.u = *reinterpret_cast<const uint2*>(pp + 32);
#pragma unroll
        for (int j = 0; j < 4; ++j) {
            const float a = (float)va.hh[j], b2 = (float)vb.hh[j];
            oa.hh[j] = (__bf16)((a * c0[j] - b2 * s0[j]) * sc);
            ob.hh[j] = (__bf16)((b2 * c1[j] + a * s1[j]) * sc);
        }
        *reinterpret_cast<uint2*>(pp)      = oa.u;
        *reinterpret_cast<uint2*>(pp + 32) = ob.u;
    }
}

// ---------------------------------------------------------------------------
// GEMM: C(MxN) = A(MxK) @ Bt(NxK)^T, bf16 in, fp32 accum.
// Ring-3 LDS, counted vmcnt(4) barriers (T3/T4). Direct-store epilogue.
// MODE 0: float output, ld = N. MODE 1 (QKV): cols <1024 -> qk buf
// [8192][1024] bf16; v -> vt[1024][4096] transposed + kappa-permuted.
// ---------------------------------------------------------------------------
template <typename OutT, int MODE>
__global__ __launch_bounds__(256) void gemm_bt(const __bf16* __restrict__ A,
                                               const __bf16* __restrict__ Bt,
                                               OutT* __restrict__ C,
                                               __bf16* __restrict__ vt,
                                               int M, int N, int K) {
    __shared__ __align__(16) __bf16 As[3][128 * 32];
    __shared__ __align__(16) __bf16 Bs[3][128 * 32];
    const int bm = blockIdx.y, bn = blockIdx.x;
    const int tid = threadIdx.x;
    const int w = tid >> 6, l = tid & 63, lg = l >> 4, lr = l & 15;
    const int wr = w >> 1, wc = w & 1;
    const __bf16* Ab = A + (size_t)(bm * 128) * K;
    const __bf16* Bb = Bt + (size_t)(bn * 128) * K;
    const int srow = tid >> 2, scol = (tid & 3) * 8;
    const __bf16* Asrc = Ab + (size_t)srow * K + scol;
    const __bf16* Bsrc = Bb + (size_t)srow * K + scol;

    auto stage = [&](int k2) {
        const int nx = k2 % 3;
        const int off = k2 * 32;
        gload16(&As[nx][tid * 8],        Asrc + off);
        gload16(&As[nx][2048 + tid * 8], Asrc + (size_t)64 * K + off);
        gload16(&Bs[nx][tid * 8],        Bsrc + off);
        gload16(&Bs[nx][2048 + tid * 8], Bsrc + (size_t)64 * K + off);
    };

    const int NS = K >> 5;
    f32x4 acc[4][4] = {};
    stage(0);
    stage(1);
    wait_barrier4();
    for (int k = 0; k < NS; ++k) {
        const bool more = (k + 2 < NS);
        if (more) stage(k + 2);
        const __bf16* Ac = &As[k % 3][0];
        const __bf16* Bc = &Bs[k % 3][0];
        bf16x8 af[4], bfr[4];
#pragma unroll
        for (int m = 0; m < 4; ++m)
            af[m] = *reinterpret_cast<const bf16x8*>(Ac + (wr * 64 + m * 16 + lr) * 32 + lg * 8);
#pragma unroll
        for (int nn = 0; nn < 4; ++nn)
            bfr[nn] = *reinterpret_cast<const bf16x8*>(Bc + (wc * 64 + nn * 16 + lr) * 32 + lg * 8);
#pragma unroll
        for (int m = 0; m < 4; ++m)
#pragma unroll
            for (int nn = 0; nn < 4; ++nn)
                acc[m][nn] = __builtin_amdgcn_mfma_f32_16x16x32_bf16(af[m], bfr[nn],
                                                                     acc[m][nn], 0, 0, 0);
        if (more) wait_barrier4();
        else      wait_barrier0();
    }
    if constexpr (MODE == 1) {
        const int cb = bn * 128 + wc * 64;
        if (cb < 1024) {                          // q,k -> qk buf (ld 1024)
#pragma unroll
            for (int m = 0; m < 4; ++m) {
                const int rg = bm * 128 + wr * 64 + m * 16 + 4 * lg;
#pragma unroll
                for (int nn = 0; nn < 4; ++nn) {
                    const int cg = cb + nn * 16 + lr;
#pragma unroll
                    for (int r = 0; r < 4; ++r)
                        C[(size_t)(rg + r) * 1024 + cg] = (OutT)acc[m][nn][r];
                }
            }
        } else {                                  // v -> vt transposed + kappa
#pragma unroll
            for (int m = 0; m < 4; ++m) {
                const int rg = bm * 128 + wr * 64 + m * 16 + 4 * lg;
                const int bidx = rg >> 12, pos0 = rg & 4095;
                const int a0 = pos0 & 63;
                const int cp = 32 * (a0 >> 5) + 8 * ((a0 >> 2) & 3) + 4 * ((a0 >> 4) & 1);
                const int nbase = (pos0 & ~63) + cp;
#pragma unroll
                for (int nn = 0; nn < 4; ++nn) {
                    const int col = cb + nn * 16 + lr - 1024;
                    const int hh = col >> 6, dd = col & 63;
                    union { __bf16 h4[4]; uint2 u; } pk2;
#pragma unroll
                    for (int r = 0; r < 4; ++r) pk2.h4[r] = (__bf16)acc[m][nn][r];
                    *reinterpret_cast<uint2*>(&vt[((size_t)(bidx * 8 + hh) * 64 + dd) * 4096 + nbase]) = pk2.u;
                }
            }
        }
        return;
    }
#pragma unroll
    for (int m = 0; m < 4; ++m) {
        const int rg = bm * 128 + wr * 64 + m * 16 + 4 * lg;
#pragma unroll
        for (int nn = 0; nn < 4; ++nn) {
            const int cg = bn * 128 + wc * 64 + nn * 16 + lr;
#pragma unroll
            for (int r = 0; r < 4; ++r)
                C[(size_t)(rg + r) * N + cg] = (OutT)acc[m][nn][r];
        }
    }
}

// ---------------------------------------------------------------------------
// Causal flash attention v13: R11 structure (1024 blocks, 3 blocks/CU,
// ring-3, zero-VALU staging, unroll x6) + row-sum l via MFMA ones-trick.
// NOTE: Lacc = mfma(ones, Pf, Lacc) performs the CROSS-LANE reduction
// internally (D[row][col] = sum over all 32 k of B) — Lacc[0] is already
// the complete row-sum; the epilogue must NOT shuffle-reduce again
// (R12's bug: double reduction -> denominator 4x -> absmax 2.6).
// ---------------------------------------------------------------------------
__global__ __launch_bounds__(256) void attn_kernel(const __bf16* __restrict__ qkp,
                                                   const __bf16* __restrict__ vt,
                                                   __bf16* __restrict__ attn_out) {
    const int bid = blockIdx.x;                      // 1024 blocks
    const int j = bid >> 3;                          // 0..127 per XCD
    const int bh = 2 * (bid & 7) + (j & 1);
    const int qt = 63 - (j >> 1);                    // heavy blocks first
    const int b = bh >> 3, h = bh & 7;
    const int tid = threadIdx.x;
    const int w = tid >> 6, l = tid & 63, lg = l >> 4, lr = l & 15;

    __shared__ __align__(16) __bf16 Ks[3][64 * 64];
    __shared__ __align__(16) __bf16 Vs[3][64 * 64];

    const __bf16* qbase = qkp + (size_t)b * 4096 * 1024 + h * 64;
    const __bf16* kbase = qbase + 512;
    const __bf16* vtb   = vt + (size_t)(b * 8 + h) * 64 * 4096;

    const int sr = tid >> 3;
    const int sc = ((tid & 7) ^ (sr & 7)) * 8;
    const __bf16* kp = kbase + (size_t)sr * 1024 + sc;
    const __bf16* vp = vtb + (size_t)sr * 4096 + sc;

    const int xel = (lr & 7) * 8;                    // read-side swizzle

    const int wq0 = qt * 64 + 16 * w;
    const int nkt = qt + 1;

    bf16x8 Qf[2];
#pragma unroll
    for (int kh = 0; kh < 2; ++kh)
        Qf[kh] = *reinterpret_cast<const bf16x8*>(
            qbase + (size_t)(wq0 + lr) * 1024 + 32 * kh + 8 * lg);

    bf16x8 ones;
#pragma unroll
    for (int i = 0; i < 8; ++i) ones[i] = (__bf16)1.0f;

    f32x4 O[4] = {};
    f32x4 Lacc = {};
    float m_ = -1e30f;

    auto stage2 = [&](__bf16* kdst, __bf16* vdst) {
        gload16(kdst + tid * 8,         kp);
        gload16(kdst + (tid + 256) * 8, kp + 32 * 1024);
        gload16(vdst + tid * 8,         vp);
        gload16(vdst + (tid + 256) * 8, vp + 32 * 4096);
        kp += 64 * 1024;
        vp += 64;
    };
    auto qk_step = [&](f32x4 (&S)[4], const __bf16* kb) {
        __builtin_amdgcn_s_setprio(1);
#pragma unroll
        for (int jt = 0; jt < 4; ++jt) {
            const __bf16* kr = kb + (16 * jt + lr) * 64;
            const bf16x8 Kf0 = *reinterpret_cast<const bf16x8*>(kr + ((8 * lg) ^ xel));
            const bf16x8 Kf1 = *reinterpret_cast<const bf16x8*>(kr + ((32 + 8 * lg) ^ xel));
            f32x4 z = {};
            z = __builtin_amdgcn_mfma_f32_16x16x32_bf16(Kf0, Qf[0], z, 0, 0, 0);
            S[jt] = __builtin_amdgcn_mfma_f32_16x16x32_bf16(Kf1, Qf[1], z, 0, 0, 0);
        }
        __builtin_amdgcn_s_setprio(0);
    };
    auto smpv = [&](f32x4 (&SC)[4], const __bf16* vb, bool domask) {
        if (domask) {
#pragma unroll
            for (int jt = 0; jt < 4; ++jt)
#pragma unroll
                for (int r = 0; r < 4; ++r)
                    if (16 * jt + 4 * lg + r > 16 * w + lr) SC[jt][r] = -1e30f;
        }
        float mx = -1e30f;
#pragma unroll
        for (int jt = 0; jt < 4; ++jt)
            mx = fmaxf(mx, fmaxf(fmaxf(SC[jt][0], SC[jt][1]), fmaxf(SC[jt][2], SC[jt][3])));
        if (__any(mx > m_ + 8.0f)) {
            mx = fmaxf(mx, __shfl_xor(mx, 16));
            mx = fmaxf(mx, __shfl_xor(mx, 32));
            const float mn = fmaxf(m_, mx);
            const float alpha = __builtin_amdgcn_exp2f(m_ - mn);
            m_ = mn;
            Lacc *= alpha;
#pragma unroll
            for (int dt = 0; dt < 4; ++dt) O[dt] *= alpha;
        }
#pragma unroll
        for (int jt = 0; jt < 4; ++jt)
#pragma unroll
            for (int r = 0; r < 4; ++r)
                SC[jt][r] = __builtin_amdgcn_exp2f(SC[jt][r] - m_);
        __builtin_amdgcn_s_setprio(1);
#pragma unroll
        for (int s = 0; s < 2; ++s) {
            bf16x8 Pf;
#pragma unroll
            for (int i = 0; i < 8; ++i)
                Pf[i] = (__bf16)SC[2 * s + (i >> 2)][i & 3];
            Lacc = __builtin_amdgcn_mfma_f32_16x16x32_bf16(ones, Pf, Lacc, 0, 0, 0);
#pragma unroll
            for (int dt = 0; dt < 4; ++dt) {
                const bf16x8 Vf = *reinterpret_cast<const bf16x8*>(
                    vb + (16 * dt + lr) * 64 + ((32 * s + 8 * lg) ^ xel));
                O[dt] = __builtin_amdgcn_mfma_f32_16x16x32_bf16(Vf, Pf, O[dt], 0, 0, 0);
            }
        }
        __builtin_amdgcn_s_setprio(0);
    };

    f32x4 S0[4], S1[4];
    int t = 0;

    // prologue: stage tiles 0,1; S0 = QK(0)
    stage2(Ks[0], Vs[0]);
    stage2(Ks[1], Vs[1]);
    __syncthreads();
    qk_step(S0, Ks[0]);

    // main loop: 6 statically-indexed bodies, all pre-diagonal
    for (; t + 8 <= nkt; t += 6) {
        stage2(Ks[2], Vs[2]); qk_step(S1, Ks[1]); smpv(S0, Vs[0], false); __syncthreads();
        stage2(Ks[0], Vs[0]); qk_step(S0, Ks[2]); smpv(S1, Vs[1], false); __syncthreads();
        stage2(Ks[1], Vs[1]); qk_step(S1, Ks[0]); smpv(S0, Vs[2], false); __syncthreads();
        stage2(Ks[2], Vs[2]); qk_step(S0, Ks[1]); smpv(S1, Vs[0], false); __syncthreads();
        stage2(Ks[0], Vs[0]); qk_step(S1, Ks[2]); smpv(S0, Vs[1], false); __syncthreads();
        stage2(Ks[1], Vs[1]); qk_step(S0, Ks[0]); smpv(S1, Vs[2], false); __syncthreads();
    }

    // tail: <=7 tiles, dynamic ring indices, mask on the last tile
    {
        f32x4 Sp[4];
#pragma unroll
        for (int jt = 0; jt < 4; ++jt) Sp[jt] = S0[jt];
        for (; t < nkt; ++t) {
            if (t + 2 < nkt) stage2(Ks[(t + 2) % 3], Vs[(t + 2) % 3]);
            f32x4 Sn[4];
            if (t + 1 < nkt) qk_step(Sn, Ks[(t + 1) % 3]);
            smpv(Sp, Vs[t % 3], t == nkt - 1);
            __syncthreads();
#pragma unroll
            for (int jt = 0; jt < 4; ++jt) Sp[jt] = Sn[jt];
        }
    }

    // epilogue: Lacc[0] is ALREADY the full row-sum (MFMA reduced across
    // lanes) — no shuffle reduce here.
    const float inv = 1.0f / Lacc[0];
    __bf16* op = attn_out + ((size_t)b * 4096 + wq0 + lr) * 512 + h * 64;
#pragma unroll
    for (int dt = 0; dt < 4; ++dt) {
        union { __bf16 h4[4]; uint2 u; } ow;
#pragma unroll
        for (int r = 0; r < 4; ++r) ow.h4[r] = (__bf16)(O[dt][r] * inv);
        *reinterpret_cast<uint2*>(op + 16 * dt + 4 * lg) = ow.u;
    }
}

// ---------------------------------------------------------------------------
extern "C" void kernel_launch(void* const* d_in, const int* in_sizes, int n_in,
                              void* d_out, int out_size, void* d_ws, size_t ws_size,
                              hipStream_t stream) {
    (void)in_sizes; (void)n_in; (void)out_size; (void)ws_size;
    const float* x    = (const float*)d_in[0];
    const float* rot  = (const float*)d_in[1];
    const float* rmsw = (const float*)d_in[2];
    const float* wqkv = (const float*)d_in[3];
    const float* wout = (const float*)d_in[4];
    float* out = (float*)d_out;

    char* ws = (char*)d_ws;
    __bf16* xn    = (__bf16*)ws;                       // 16,777,216 B
    __bf16* wqkvt = (__bf16*)(ws + 16777216);          //  3,145,728 B
    __bf16* woutt = (__bf16*)(ws + 16777216 + 3145728);//  1,048,576 B
    __bf16* aout  = (__bf16*)(ws + 16777216 + 3145728 + 1048576); // 8,388,608 B
    // d_out during pipeline: qk [0,16.78M), csin [16.78M,18.87M),
    // vt [18.87M,27.26M) — all dead before the final GEMM overwrites d_out.
    __bf16* qk   = (__bf16*)d_out;
    float2* csin = (float2*)((char*)d_out + 16777216);
    __bf16* vt   = (__bf16*)((char*)d_out + 18874368);

    rmsnorm_kernel<<<8192, 256, 0, stream>>>(x, rmsw, xn);
    transpose_cast_kernel<<<dim3(48, 32), dim3(32, 8), 0, stream>>>(wqkv, wqkvt, 1024, 1536);
    transpose_cast_kernel<<<dim3(32, 16), dim3(32, 8), 0, stream>>>(wout, woutt, 512, 1024);
    csin_kernel<<<1024, 256, 0, stream>>>(rot, csin);
    gemm_bt<__bf16, 1><<<dim3(12, 64), 256, 0, stream>>>(xn, wqkvt, qk, vt, 8192, 1536, 1024);
    rope_kernel<<<2048, 256, 0, stream>>>(qk, csin);
    attn_kernel<<<1024, 256, 0, stream>>>(qk, vt, aout);
    gemm_bt<float, 0><<<dim3(8, 64), 256, 0, stream>>>(aout, woutt, out, nullptr, 8192, 1024, 512);
}

// Round 14
// 136.705 us; speedup vs baseline: 1.0665x; 1.0140x over previous
//
#include <hip/hip_runtime.h>
#include <hip/hip_bf16.h>
#include <cstdint>

using bf16x8 = __attribute__((ext_vector_type(8))) __bf16;
using f32x4  = __attribute__((ext_vector_type(4))) float;

#define LOG2E 1.4426950408889634f

__device__ inline void gload16(__bf16* lds, const __bf16* g) {
    __builtin_amdgcn_global_load_lds((const __attribute__((address_space(1))) void*)g,
                                     (__attribute__((address_space(3))) void*)lds, 16, 0, 0);
}
__device__ inline void wait_barrier4() {
    asm volatile("s_waitcnt vmcnt(4)" ::: "memory");
    __builtin_amdgcn_s_barrier();
}
__device__ inline void wait_barrier0() {
    asm volatile("s_waitcnt vmcnt(0)" ::: "memory");
    __builtin_amdgcn_s_barrier();
}

// ---------------------------------------------------------------------------
// RMSNorm: one block (256 threads) per row of 1024 fp32 -> bf16
// ---------------------------------------------------------------------------
__global__ __launch_bounds__(256) void rmsnorm_kernel(const float* __restrict__ x,
                                                      const float* __restrict__ w,
                                                      __bf16* __restrict__ xn) {
    const int row = blockIdx.x;
    const float4 v = reinterpret_cast<const float4*>(x + (size_t)row * 1024)[threadIdx.x];
    float ss = v.x * v.x + v.y * v.y + v.z * v.z + v.w * v.w;
#pragma unroll
    for (int i = 1; i < 64; i <<= 1) ss += __shfl_xor(ss, i);
    __shared__ float part[4];
    if ((threadIdx.x & 63) == 0) part[threadIdx.x >> 6] = ss;
    __syncthreads();
    const float total = part[0] + part[1] + part[2] + part[3];
    const float scale = rsqrtf(total * (1.0f / 1024.0f) + 1.1920929e-07f);
    const float4 wv = reinterpret_cast<const float4*>(w)[threadIdx.x];
    union { __bf16 h[4]; uint2 u; } pk;
    pk.h[0] = (__bf16)(v.x * scale * wv.x);
    pk.h[1] = (__bf16)(v.y * scale * wv.y);
    pk.h[2] = (__bf16)(v.z * scale * wv.z);
    pk.h[3] = (__bf16)(v.w * scale * wv.w);
    reinterpret_cast<uint2*>(xn + (size_t)row * 1024)[threadIdx.x] = pk.u;
}

// ---------------------------------------------------------------------------
// Transpose + cast: in (K x N) fp32 row-major -> out (N x K) bf16 row-major
// ---------------------------------------------------------------------------
__global__ void transpose_cast_kernel(const float* __restrict__ in,
                                      __bf16* __restrict__ out, int K, int N) {
    __shared__ float tile[32][33];
    const int n0 = blockIdx.x * 32, k0 = blockIdx.y * 32;
#pragma unroll
    for (int r = threadIdx.y; r < 32; r += 8)
        tile[r][threadIdx.x] = in[(size_t)(k0 + r) * N + n0 + threadIdx.x];
    __syncthreads();
#pragma unroll
    for (int r = threadIdx.y; r < 32; r += 8)
        out[(size_t)(n0 + r) * K + k0 + threadIdx.x] = (__bf16)tile[threadIdx.x][r];
}

// ---------------------------------------------------------------------------
// cos/sin table: csin[pos*64+d] = (cos, sin) of rot[pos][d]. 262144 entries.
// ---------------------------------------------------------------------------
__global__ __launch_bounds__(256) void csin_kernel(const float* __restrict__ rot,
                                                   float2* __restrict__ csin) {
    const int i = blockIdx.x * 256 + threadIdx.x;
    float s, c;
    sincosf(rot[i], &s, &c);
    csin[i] = make_float2(c, s);
}

// ---------------------------------------------------------------------------
// RoPE (table-based) in-place on the K half of qk [8192][1024] only
// (Q rope is fused into attn's register Q load). One wave per (b,pos).
// ---------------------------------------------------------------------------
__global__ __launch_bounds__(256) void rope_k_kernel(__bf16* __restrict__ qk,
                                                     const float2* __restrict__ csin) {
    const int row = blockIdx.x * 4 + (threadIdx.x >> 6);   // b*4096+pos
    const int lane = threadIdx.x & 63;
    const int h = lane >> 3, dl = (lane & 7) * 4;
    const int pos = row & 4095;
    const float4 csA = *reinterpret_cast<const float4*>(&csin[pos * 64 + dl]);
    const float4 csB = *reinterpret_cast<const float4*>(&csin[pos * 64 + dl + 2]);
    const float4 csC = *reinterpret_cast<const float4*>(&csin[pos * 64 + dl + 32]);
    const float4 csD = *reinterpret_cast<const float4*>(&csin[pos * 64 + dl + 34]);
    const float c0[4] = {csA.x, csA.z, csB.x, csB.z};
    const float s0[4] = {csA.y, csA.w, csB.y, csB.w};
    const float c1[4] = {csC.x, csC.z, csD.x, csD.z};
    const float s1[4] = {csC.y, csC.w, csD.y, csD.w};
    __bf16* pp = qk + (size_t)row * 1024 + 512 + h * 64 + dl;
    union { uint2 u; __bf16 hh[4]; } va, vb, oa, ob;
    va.u = *reinterpret_cast<const uint2*>(pp);
    vb.u = *reinterpret_cast<const uint2*>(pp + 32);
#pragma unroll
    for (int j = 0; j < 4; ++j) {
        const float a = (float)va.hh[j], b2 = (float)vb.hh[j];
        oa.hh[j] = (__bf16)(a * c0[j] - b2 * s0[j]);
        ob.hh[j] = (__bf16)(b2 * c1[j] + a * s1[j]);
    }
    *reinterpret_cast<uint2*>(pp)      = oa.u;
    *reinterpret_cast<uint2*>(pp + 32) = ob.u;
}

// ---------------------------------------------------------------------------
// GEMM: C(MxN) = A(MxK) @ Bt(NxK)^T, bf16 in, fp32 accum.
// Ring-3 LDS, counted vmcnt(4) barriers. 1-D grid with bijective XCD
// swizzle (T1): each XCD owns 8 consecutive bm rows x all bn -> A panels
// L2-resident per XCD. Requires M == 8192 (8 bm rows per XCD).
// MODE 0: float output, ld = N. MODE 1 (QKV): cols <1024 -> qk buf
// [8192][1024] bf16 (RAW q/k, rope applied later); v -> vt[1024][4096]
// transposed + kappa-permuted.
// ---------------------------------------------------------------------------
template <typename OutT, int MODE>
__global__ __launch_bounds__(256) void gemm_bt(const __bf16* __restrict__ A,
                                               const __bf16* __restrict__ Bt,
                                               OutT* __restrict__ C,
                                               __bf16* __restrict__ vt,
                                               int M, int N, int K) {
    __shared__ __align__(16) __bf16 As[3][128 * 32];
    __shared__ __align__(16) __bf16 Bs[3][128 * 32];
    const int nbn = N >> 7;
    const int xcd = blockIdx.x & 7;
    const int idx = blockIdx.x >> 3;
    const int bm = xcd * 8 + idx / nbn;
    const int bn = idx % nbn;
    const int tid = threadIdx.x;
    const int w = tid >> 6, l = tid & 63, lg = l >> 4, lr = l & 15;
    const int wr = w >> 1, wc = w & 1;
    const __bf16* Ab = A + (size_t)(bm * 128) * K;
    const __bf16* Bb = Bt + (size_t)(bn * 128) * K;
    const int srow = tid >> 2, scol = (tid & 3) * 8;
    const __bf16* Asrc = Ab + (size_t)srow * K + scol;
    const __bf16* Bsrc = Bb + (size_t)srow * K + scol;

    auto stage = [&](int k2) {
        const int nx = k2 % 3;
        const int off = k2 * 32;
        gload16(&As[nx][tid * 8],        Asrc + off);
        gload16(&As[nx][2048 + tid * 8], Asrc + (size_t)64 * K + off);
        gload16(&Bs[nx][tid * 8],        Bsrc + off);
        gload16(&Bs[nx][2048 + tid * 8], Bsrc + (size_t)64 * K + off);
    };

    const int NS = K >> 5;
    f32x4 acc[4][4] = {};
    stage(0);
    stage(1);
    wait_barrier4();
    for (int k = 0; k < NS; ++k) {
        const bool more = (k + 2 < NS);
        if (more) stage(k + 2);
        const __bf16* Ac = &As[k % 3][0];
        const __bf16* Bc = &Bs[k % 3][0];
        bf16x8 af[4], bfr[4];
#pragma unroll
        for (int m = 0; m < 4; ++m)
            af[m] = *reinterpret_cast<const bf16x8*>(Ac + (wr * 64 + m * 16 + lr) * 32 + lg * 8);
#pragma unroll
        for (int nn = 0; nn < 4; ++nn)
            bfr[nn] = *reinterpret_cast<const bf16x8*>(Bc + (wc * 64 + nn * 16 + lr) * 32 + lg * 8);
#pragma unroll
        for (int m = 0; m < 4; ++m)
#pragma unroll
            for (int nn = 0; nn < 4; ++nn)
                acc[m][nn] = __builtin_amdgcn_mfma_f32_16x16x32_bf16(af[m], bfr[nn],
                                                                     acc[m][nn], 0, 0, 0);
        if (more) wait_barrier4();
        else      wait_barrier0();
    }
    if constexpr (MODE == 1) {
        const int cb = bn * 128 + wc * 64;
        if (cb < 1024) {                          // q,k -> qk buf (ld 1024)
#pragma unroll
            for (int m = 0; m < 4; ++m) {
                const int rg = bm * 128 + wr * 64 + m * 16 + 4 * lg;
#pragma unroll
                for (int nn = 0; nn < 4; ++nn) {
                    const int cg = cb + nn * 16 + lr;
#pragma unroll
                    for (int r = 0; r < 4; ++r)
                        C[(size_t)(rg + r) * 1024 + cg] = (OutT)acc[m][nn][r];
                }
            }
        } else {                                  // v -> vt transposed + kappa
#pragma unroll
            for (int m = 0; m < 4; ++m) {
                const int rg = bm * 128 + wr * 64 + m * 16 + 4 * lg;
                const int bidx = rg >> 12, pos0 = rg & 4095;
                const int a0 = pos0 & 63;
                const int cp = 32 * (a0 >> 5) + 8 * ((a0 >> 2) & 3) + 4 * ((a0 >> 4) & 1);
                const int nbase = (pos0 & ~63) + cp;
#pragma unroll
                for (int nn = 0; nn < 4; ++nn) {
                    const int col = cb + nn * 16 + lr - 1024;
                    const int hh = col >> 6, dd = col & 63;
                    union { __bf16 h4[4]; uint2 u; } pk2;
#pragma unroll
                    for (int r = 0; r < 4; ++r) pk2.h4[r] = (__bf16)acc[m][nn][r];
                    *reinterpret_cast<uint2*>(&vt[((size_t)(bidx * 8 + hh) * 64 + dd) * 4096 + nbase]) = pk2.u;
                }
            }
        }
        return;
    }
#pragma unroll
    for (int m = 0; m < 4; ++m) {
        const int rg = bm * 128 + wr * 64 + m * 16 + 4 * lg;
#pragma unroll
        for (int nn = 0; nn < 4; ++nn) {
            const int cg = bn * 128 + wc * 64 + nn * 16 + lr;
#pragma unroll
            for (int r = 0; r < 4; ++r)
                C[(size_t)(rg + r) * N + cg] = (OutT)acc[m][nn][r];
        }
    }
}

// ---------------------------------------------------------------------------
// Causal flash attention v14: K ring-2 + V ring-3 = 40KB LDS -> 4 blocks/CU
// (16 waves/CU, grid-exact). Q-rope fused at register Q load (Q read once;
// pairs (d,d+32) = Qf[0][i],Qf[1][i] same lane). Row-sum l via MFMA
// ones-trick (Lacc[0] = full row-sum, no epilogue shuffle). Zero-VALU
// staging, P in registers (kappa vt), defer-max, unroll x6 static.
// Extra prologue barrier: body-0's stage writes Ks[0] which prologue QK read.
// ---------------------------------------------------------------------------
__global__ __launch_bounds__(256) void attn_kernel(const __bf16* __restrict__ qkp,
                                                   const __bf16* __restrict__ vt,
                                                   const float2* __restrict__ csin,
                                                   __bf16* __restrict__ attn_out) {
    const int bid = blockIdx.x;                      // 1024 blocks
    const int j = bid >> 3;                          // 0..127 per XCD
    const int bh = 2 * (bid & 7) + (j & 1);
    const int qt = 63 - (j >> 1);                    // heavy blocks first
    const int b = bh >> 3, h = bh & 7;
    const int tid = threadIdx.x;
    const int w = tid >> 6, l = tid & 63, lg = l >> 4, lr = l & 15;

    __shared__ __align__(16) __bf16 Ks[2][64 * 64];
    __shared__ __align__(16) __bf16 Vs[3][64 * 64];

    const __bf16* qbase = qkp + (size_t)b * 4096 * 1024 + h * 64;
    const __bf16* kbase = qbase + 512;
    const __bf16* vtb   = vt + (size_t)(b * 8 + h) * 64 * 4096;

    const int sr = tid >> 3;
    const int sc = ((tid & 7) ^ (sr & 7)) * 8;
    const __bf16* kp = kbase + (size_t)sr * 1024 + sc;
    const __bf16* vp = vtb + (size_t)sr * 4096 + sc;

    const int xel = (lr & 7) * 8;                    // read-side swizzle

    const int wq0 = qt * 64 + 16 * w;
    const int nkt = qt + 1;

    auto stage2 = [&](__bf16* kdst, __bf16* vdst) {
        gload16(kdst + tid * 8,         kp);
        gload16(kdst + (tid + 256) * 8, kp + 32 * 1024);
        gload16(vdst + tid * 8,         vp);
        gload16(vdst + (tid + 256) * 8, vp + 32 * 4096);
        kp += 64 * 1024;
        vp += 64;
    };

    // prologue part 1: start staging tiles 0,1 (loads fly under Q-rope VALU)
    stage2(Ks[0], Vs[0]);
    stage2(Ks[1], Vs[1]);

    // Q load + fused rope (+ 1/sqrt(d) * log2e scale)
    bf16x8 Qf[2];
    {
        const __bf16* qp = qbase + (size_t)(wq0 + lr) * 1024 + 8 * lg;
        const bf16x8 rq0 = *reinterpret_cast<const bf16x8*>(qp);
        const bf16x8 rq1 = *reinterpret_cast<const bf16x8*>(qp + 32);
        const float2* csp = csin + (size_t)(wq0 + lr) * 64 + 8 * lg;
        const float qs = 0.125f * LOG2E;
#pragma unroll
        for (int i = 0; i < 8; ++i) {
            const float2 ca = csp[i];
            const float2 cb = csp[i + 32];
            const float a = (float)rq0[i], b2 = (float)rq1[i];
            Qf[0][i] = (__bf16)((a * ca.x - b2 * ca.y) * qs);
            Qf[1][i] = (__bf16)((b2 * cb.x + a * cb.y) * qs);
        }
    }

    bf16x8 ones;
#pragma unroll
    for (int i = 0; i < 8; ++i) ones[i] = (__bf16)1.0f;

    f32x4 O[4] = {};
    f32x4 Lacc = {};
    float m_ = -1e30f;

    auto qk_step = [&](f32x4 (&S)[4], const __bf16* kb) {
        __builtin_amdgcn_s_setprio(1);
#pragma unroll
        for (int jt = 0; jt < 4; ++jt) {
            const __bf16* kr = kb + (16 * jt + lr) * 64;
            const bf16x8 Kf0 = *reinterpret_cast<const bf16x8*>(kr + ((8 * lg) ^ xel));
            const bf16x8 Kf1 = *reinterpret_cast<const bf16x8*>(kr + ((32 + 8 * lg) ^ xel));
            f32x4 z = {};
            z = __builtin_amdgcn_mfma_f32_16x16x32_bf16(Kf0, Qf[0], z, 0, 0, 0);
            S[jt] = __builtin_amdgcn_mfma_f32_16x16x32_bf16(Kf1, Qf[1], z, 0, 0, 0);
        }
        __builtin_amdgcn_s_setprio(0);
    };
    auto smpv = [&](f32x4 (&SC)[4], const __bf16* vb, bool domask) {
        if (domask) {
#pragma unroll
            for (int jt = 0; jt < 4; ++jt)
#pragma unroll
                for (int r = 0; r < 4; ++r)
                    if (16 * jt + 4 * lg + r > 16 * w + lr) SC[jt][r] = -1e30f;
        }
        float mx = -1e30f;
#pragma unroll
        for (int jt = 0; jt < 4; ++jt)
            mx = fmaxf(mx, fmaxf(fmaxf(SC[jt][0], SC[jt][1]), fmaxf(SC[jt][2], SC[jt][3])));
        if (__any(mx > m_ + 8.0f)) {
            mx = fmaxf(mx, __shfl_xor(mx, 16));
            mx = fmaxf(mx, __shfl_xor(mx, 32));
            const float mn = fmaxf(m_, mx);
            const float alpha = __builtin_amdgcn_exp2f(m_ - mn);
            m_ = mn;
            Lacc *= alpha;
#pragma unroll
            for (int dt = 0; dt < 4; ++dt) O[dt] *= alpha;
        }
#pragma unroll
        for (int jt = 0; jt < 4; ++jt)
#pragma unroll
            for (int r = 0; r < 4; ++r)
                SC[jt][r] = __builtin_amdgcn_exp2f(SC[jt][r] - m_);
        __builtin_amdgcn_s_setprio(1);
#pragma unroll
        for (int s = 0; s < 2; ++s) {
            bf16x8 Pf;
#pragma unroll
            for (int i = 0; i < 8; ++i)
                Pf[i] = (__bf16)SC[2 * s + (i >> 2)][i & 3];
            Lacc = __builtin_amdgcn_mfma_f32_16x16x32_bf16(ones, Pf, Lacc, 0, 0, 0);
#pragma unroll
            for (int dt = 0; dt < 4; ++dt) {
                const bf16x8 Vf = *reinterpret_cast<const bf16x8*>(
                    vb + (16 * dt + lr) * 64 + ((32 * s + 8 * lg) ^ xel));
                O[dt] = __builtin_amdgcn_mfma_f32_16x16x32_bf16(Vf, Pf, O[dt], 0, 0, 0);
            }
        }
        __builtin_amdgcn_s_setprio(0);
    };

    f32x4 S0[4], S1[4];
    int t = 0;

    // prologue part 2: tiles 0,1 landed; S0 = QK(0); extra barrier so the
    // first loop body may overwrite Ks[0] (K ring-2 hazard).
    __syncthreads();
    qk_step(S0, Ks[0]);
    __syncthreads();

    // main loop: 6 statically-indexed bodies (K parity 2, V ring 3, S parity
    // 2), all pre-diagonal. Body j (tile t+j): stage tile t+j+2 into
    // K[(j)&1]/V[(j+2)%3]; qk tile t+j+1 from K[(j+1)&1]; smpv tile t+j.
    for (; t + 8 <= nkt; t += 6) {
        stage2(Ks[0], Vs[2]); qk_step(S1, Ks[1]); smpv(S0, Vs[0], false); __syncthreads();
        stage2(Ks[1], Vs[0]); qk_step(S0, Ks[0]); smpv(S1, Vs[1], false); __syncthreads();
        stage2(Ks[0], Vs[1]); qk_step(S1, Ks[1]); smpv(S0, Vs[2], false); __syncthreads();
        stage2(Ks[1], Vs[2]); qk_step(S0, Ks[0]); smpv(S1, Vs[0], false); __syncthreads();
        stage2(Ks[0], Vs[0]); qk_step(S1, Ks[1]); smpv(S0, Vs[1], false); __syncthreads();
        stage2(Ks[1], Vs[1]); qk_step(S0, Ks[0]); smpv(S1, Vs[2], false); __syncthreads();
    }

    // tail: <=7 tiles, dynamic indices, mask on the last tile
    {
        f32x4 Sp[4];
#pragma unroll
        for (int jt = 0; jt < 4; ++jt) Sp[jt] = S0[jt];
        for (; t < nkt; ++t) {
            if (t + 2 < nkt) stage2(Ks[(t + 2) & 1], Vs[(t + 2) % 3]);
            f32x4 Sn[4];
            if (t + 1 < nkt) qk_step(Sn, Ks[(t + 1) & 1]);
            smpv(Sp, Vs[t % 3], t == nkt - 1);
            __syncthreads();
#pragma unroll
            for (int jt = 0; jt < 4; ++jt) Sp[jt] = Sn[jt];
        }
    }

    // epilogue: Lacc[0] is already the full row-sum (MFMA cross-lane reduce)
    const float inv = 1.0f / Lacc[0];
    __bf16* op = attn_out + ((size_t)b * 4096 + wq0 + lr) * 512 + h * 64;
#pragma unroll
    for (int dt = 0; dt < 4; ++dt) {
        union { __bf16 h4[4]; uint2 u; } ow;
#pragma unroll
        for (int r = 0; r < 4; ++r) ow.h4[r] = (__bf16)(O[dt][r] * inv);
        *reinterpret_cast<uint2*>(op + 16 * dt + 4 * lg) = ow.u;
    }
}

// ---------------------------------------------------------------------------
extern "C" void kernel_launch(void* const* d_in, const int* in_sizes, int n_in,
                              void* d_out, int out_size, void* d_ws, size_t ws_size,
                              hipStream_t stream) {
    (void)in_sizes; (void)n_in; (void)out_size; (void)ws_size;
    const float* x    = (const float*)d_in[0];
    const float* rot  = (const float*)d_in[1];
    const float* rmsw = (const float*)d_in[2];
    const float* wqkv = (const float*)d_in[3];
    const float* wout = (const float*)d_in[4];
    float* out = (float*)d_out;

    char* ws = (char*)d_ws;
    __bf16* xn    = (__bf16*)ws;                       // 16,777,216 B
    __bf16* wqkvt = (__bf16*)(ws + 16777216);          //  3,145,728 B
    __bf16* woutt = (__bf16*)(ws + 16777216 + 3145728);//  1,048,576 B
    __bf16* aout  = (__bf16*)(ws + 16777216 + 3145728 + 1048576); // 8,388,608 B
    // d_out during pipeline: qk [0,16.78M), csin [16.78M,18.87M),
    // vt [18.87M,27.26M) — all dead before the final GEMM overwrites d_out.
    __bf16* qk   = (__bf16*)d_out;
    float2* csin = (float2*)((char*)d_out + 16777216);
    __bf16* vt   = (__bf16*)((char*)d_out + 18874368);

    rmsnorm_kernel<<<8192, 256, 0, stream>>>(x, rmsw, xn);
    transpose_cast_kernel<<<dim3(48, 32), dim3(32, 8), 0, stream>>>(wqkv, wqkvt, 1024, 1536);
    transpose_cast_kernel<<<dim3(32, 16), dim3(32, 8), 0, stream>>>(wout, woutt, 512, 1024);
    csin_kernel<<<1024, 256, 0, stream>>>(rot, csin);
    gemm_bt<__bf16, 1><<<768, 256, 0, stream>>>(xn, wqkvt, qk, vt, 8192, 1536, 1024);
    rope_k_kernel<<<2048, 256, 0, stream>>>(qk, csin);
    attn_kernel<<<1024, 256, 0, stream>>>(qk, vt, csin, aout);
    gemm_bt<float, 0><<<512, 256, 0, stream>>>(aout, woutt, out, nullptr, 8192, 1024, 512);
}